// Round 7
// baseline (507.949 us; speedup 1.0000x reference)
//
#include <hip/hip_runtime.h>

#define EPS 1e-5f
#define APITCH 264   // bf16 tile row pitch (shorts)

typedef __attribute__((ext_vector_type(8))) short bf16x8;
typedef __attribute__((ext_vector_type(4))) float f32x4;

// RTNE (one-time weight conversion)
__device__ __forceinline__ unsigned short f2b_rtne(float f) {
  unsigned u = __builtin_bit_cast(unsigned, f);
  u += 0x7fffu + ((u >> 16) & 1u);
  return (unsigned short)(u >> 16);
}
// fast round-half-up bf16
__device__ __forceinline__ unsigned short f2bf(float f) {
  unsigned u = __builtin_bit_cast(unsigned, f);
  return (unsigned short)((u + 0x8000u) >> 16);
}
// HW packed f32->2xbf16 (RTNE)
__device__ __forceinline__ unsigned cvt_pk(float lo, float hi) {
  unsigned r;
  asm("v_cvt_pk_bf16_f32 %0, %1, %2" : "=v"(r) : "v"(lo), "v"(hi));
  return r;
}
__device__ __forceinline__ float bhalf(unsigned pk, int hi) {
  unsigned u = hi ? (pk & 0xffff0000u) : (pk << 16);
  return __builtin_bit_cast(float, u);
}
__device__ __forceinline__ int div9(int r) {
  return (int)(__umulhi((unsigned)r, 954437177u) >> 1);
}

// Convert all 5 weight matrices into MFMA-fragment-linear bf16 (contiguous dst).
__global__ void k_cvt_all(const float* __restrict__ dynW, const float* __restrict__ inpW,
                          const float* __restrict__ igW, const float* __restrict__ ugW,
                          const float* __restrict__ fcW, unsigned short* __restrict__ dst) {
  int i = blockIdx.x * blockDim.x + threadIdx.x;   // [0, 458752)
  const float* src; int off;
  if (i < 131072)      { src = dynW; off = i; }
  else if (i < 262144) { src = inpW; off = i - 131072; }
  else if (i < 327680) { src = igW;  off = i - 262144; }
  else if (i < 393216) { src = ugW;  off = i - 327680; }
  else                 { src = fcW;  off = i - 393216; }
  int j = off & 7, lane = (off >> 3) & 63, kk = (off >> 9) & 7, ct = off >> 12;
  int row = ct * 16 + (lane & 15);
  int col = kk * 32 + (lane >> 4) * 8 + j;
  dst[i] = f2b_rtne(src[row * 256 + col]);
}

// ================= 64-row main kernel =================

__device__ __forceinline__ void loadA64(const short* src, bf16x8 (&a)[2][2][8],
                                        int lr, int lh) {
#pragma unroll
  for (int rg = 0; rg < 2; rg++)
#pragma unroll
    for (int rh = 0; rh < 2; rh++)
#pragma unroll
      for (int kk = 0; kk < 8; kk++)
        a[rg][rh][kk] = *(const bf16x8*)&src[(rg * 32 + rh * 16 + lr) * APITCH + kk * 32 + lh * 8];
}

// 64 rows x 64 cols; b[8] per q reused across 4 row-fragments (2x MFMA:load vs 32-row)
__device__ __forceinline__ void gemm64(const bf16x8 (&a)[2][2][8],
                                       const unsigned short* __restrict__ W,
                                       f32x4 (&acc)[4][2][2], int wv, int lane) {
#pragma unroll
  for (int q = 0; q < 4; q++) {
    const unsigned short* Wp = W + ((wv * 4 + q) << 12) + lane * 8;
    bf16x8 b[8];
#pragma unroll
    for (int kk = 0; kk < 8; kk++) b[kk] = *(const bf16x8*)&Wp[kk * 512];
#pragma unroll
    for (int rg = 0; rg < 2; rg++)
#pragma unroll
      for (int rh = 0; rh < 2; rh++) {
        acc[q][rg][rh] = (f32x4){0.f, 0.f, 0.f, 0.f};
#pragma unroll
        for (int kk = 0; kk < 8; kk++)
          acc[q][rg][rh] = __builtin_amdgcn_mfma_f32_16x16x32_bf16(
              a[rg][rh][kk], b[kk], acc[q][rg][rh], 0, 0, 0);
      }
  }
}

__device__ __forceinline__ void statsW64(const f32x4 (&acc)[4][2][2], const float (&b4)[4],
                                         float* sP, float* qP, int wv, int lr, int lh) {
#pragma unroll
  for (int rg = 0; rg < 2; rg++)
#pragma unroll
    for (int rh = 0; rh < 2; rh++)
#pragma unroll
      for (int i = 0; i < 4; i++) {
        float s = 0.f, qq = 0.f;
#pragma unroll
        for (int q = 0; q < 4; q++) { float v = acc[q][rg][rh][i] + b4[q]; s += v; qq += v * v; }
#pragma unroll
        for (int m = 1; m < 16; m <<= 1) { s += __shfl_xor(s, m); qq += __shfl_xor(qq, m); }
        if (lr == 0) {
          int rr = rg * 32 + rh * 16 + lh * 4 + i;
          sP[wv * 64 + rr] = s; qP[wv * 64 + rr] = qq;
        }
      }
}
__device__ __forceinline__ void muRs(const float* sP, const float* qP, int rr,
                                     float& mu, float& rs) {
  float S = sP[rr] + sP[64 + rr] + sP[128 + rr] + sP[192 + rr];
  float Q = qP[rr] + qP[64 + rr] + qP[128 + rr] + qP[192 + rr];
  mu = S * (1.f / 256.f);
  rs = rsqrtf(Q * (1.f / 256.f) - mu * mu + EPS);
}

// NOTE: no min-waves arg — a second __launch_bounds__ argument halves usable
// arch-VGPR on MFMA kernels (observed cap = 256/minwaves, R2-R4) and forces scratch.
__global__ __launch_bounds__(256) void k_main64(
    const float* __restrict__ inf,
    const unsigned short* __restrict__ inpWf, const float* __restrict__ inpb,
    const unsigned short* __restrict__ igWf, const float* __restrict__ igb,
    const unsigned short* __restrict__ ugWf, const float* __restrict__ ugb,
    const unsigned short* __restrict__ fcWf, const float* __restrict__ fcb,
    const float* __restrict__ nig, const float* __restrict__ nib,
    const float* __restrict__ iig, const float* __restrict__ iib,
    const float* __restrict__ iog, const float* __restrict__ iob,
    const float* __restrict__ fng, const float* __restrict__ fnb,
    const float* __restrict__ param_in, const float* __restrict__ param_out_ln,
    float* __restrict__ out) {
  __shared__ short aT[64 * APITCH];
  __shared__ short gT[64 * APITCH];
  __shared__ float sPP[2][256], qPP[2][256];

  const int t = threadIdx.x;
  const int wv = t >> 6, lane = t & 63, lr = lane & 15, lh = lane >> 4;
  const int cb = wv * 64;
  const int r0 = blockIdx.x * 64;

  // stage 64x256 f32 -> bf16 LDS
#pragma unroll
  for (int j = 0; j < 16; j++) {
    const int idx4 = j * 256 + t;
    const int row = idx4 >> 6;
    const int c4 = (idx4 & 63) << 2;
    const float4 v = *(const float4*)&inf[(size_t)(r0 + row) * 256 + c4];
    uint2 pk;
    pk.x = cvt_pk(v.x, v.y);
    pk.y = cvt_pk(v.z, v.w);
    *(uint2*)&aT[row * APITCH + c4] = pk;
  }
  __syncthreads();

  bf16x8 a[2][2][8];
  f32x4 acc[4][2][2];
  float b4[4], gA[4], bB[4];
  unsigned gio[4][2][2][2];

  loadA64(aT, a, lr, lh);

  // ---- PH0: input_in -> gate_feats -> gT ----
  gemm64(a, inpWf, acc, wv, lane);
#pragma unroll
  for (int q = 0; q < 4; q++) b4[q] = inpb[cb + q * 16 + lr];
#pragma unroll
  for (int rg = 0; rg < 2; rg++)
#pragma unroll
    for (int rh = 0; rh < 2; rh++)
#pragma unroll
      for (int i = 0; i < 4; i++) {
        const int rr = rg * 32 + rh * 16 + lh * 4 + i;
        const float* pin = param_in + (size_t)div9(r0 + rr) * 256;
#pragma unroll
        for (int q = 0; q < 4; q++) {
          const int col = cb + q * 16 + lr;
          float g = (acc[q][rg][rh][i] + b4[q]) * pin[col];
          gT[rr * APITCH + col] = (short)f2bf(g);
        }
      }

  // ---- PH1: input_out, LN -> gio ----
  gemm64(a, inpWf + (16 << 12), acc, wv, lane);
#pragma unroll
  for (int q = 0; q < 4; q++) b4[q] = inpb[256 + cb + q * 16 + lr];
  statsW64(acc, b4, sPP[1], qPP[1], wv, lr, lh);
  __syncthreads();
#pragma unroll
  for (int q = 0; q < 4; q++) { gA[q] = iog[cb + q * 16 + lr]; bB[q] = iob[cb + q * 16 + lr]; }
#pragma unroll
  for (int rg = 0; rg < 2; rg++)
#pragma unroll
    for (int rh = 0; rh < 2; rh++) {
      float vv[4][4];
#pragma unroll
      for (int i = 0; i < 4; i++) {
        const int rr = rg * 32 + rh * 16 + lh * 4 + i;
        float mu, rs;
        muRs(sPP[1], qPP[1], rr, mu, rs);
#pragma unroll
        for (int q = 0; q < 4; q++)
          vv[q][i] = (acc[q][rg][rh][i] + b4[q] - mu) * rs * gA[q] + bB[q];
      }
#pragma unroll
      for (int q = 0; q < 4; q++) {
        gio[q][rg][rh][0] = cvt_pk(vv[q][0], vv[q][1]);
        gio[q][rg][rh][1] = cvt_pk(vv[q][2], vv[q][3]);
      }
    }

  // ---- PH2: ig gate; gio <- g1 * ioLN ----
  loadA64(gT, a, lr, lh);
  gemm64(a, igWf, acc, wv, lane);
#pragma unroll
  for (int q = 0; q < 4; q++) b4[q] = igb[cb + q * 16 + lr];
  statsW64(acc, b4, sPP[0], qPP[0], wv, lr, lh);
  __syncthreads();
#pragma unroll
  for (int q = 0; q < 4; q++) { gA[q] = iig[cb + q * 16 + lr]; bB[q] = iib[cb + q * 16 + lr]; }
#pragma unroll
  for (int rg = 0; rg < 2; rg++)
#pragma unroll
    for (int rh = 0; rh < 2; rh++) {
      float vv[4][4];
#pragma unroll
      for (int i = 0; i < 4; i++) {
        const int rr = rg * 32 + rh * 16 + lh * 4 + i;
        float mu, rs;
        muRs(sPP[0], qPP[0], rr, mu, rs);
#pragma unroll
        for (int q = 0; q < 4; q++) {
          float p = (acc[q][rg][rh][i] + b4[q] - mu) * rs * gA[q] + bB[q];
          float g1 = 1.f / (1.f + __expf(-p));
          vv[q][i] = g1 * bhalf(gio[q][rg][rh][i >> 1], i & 1);
        }
      }
#pragma unroll
      for (int q = 0; q < 4; q++) {
        gio[q][rg][rh][0] = cvt_pk(vv[q][0], vv[q][1]);
        gio[q][rg][rh][1] = cvt_pk(vv[q][2], vv[q][3]);
      }
    }

  // ---- PH3: ug gate; features -> aT ----
  gemm64(a, ugWf, acc, wv, lane);
#pragma unroll
  for (int q = 0; q < 4; q++) b4[q] = ugb[cb + q * 16 + lr];
  statsW64(acc, b4, sPP[1], qPP[1], wv, lr, lh);
  __syncthreads();
#pragma unroll
  for (int q = 0; q < 4; q++) { gA[q] = nig[cb + q * 16 + lr]; bB[q] = nib[cb + q * 16 + lr]; }
#pragma unroll
  for (int rg = 0; rg < 2; rg++)
#pragma unroll
    for (int rh = 0; rh < 2; rh++)
#pragma unroll
      for (int i = 0; i < 4; i++) {
        const int rr = rg * 32 + rh * 16 + lh * 4 + i;
        float mu, rs;
        muRs(sPP[1], qPP[1], rr, mu, rs);
        const float* po = param_out_ln + (size_t)div9(r0 + rr) * 256;
#pragma unroll
        for (int q = 0; q < 4; q++) {
          const int col = cb + q * 16 + lr;
          float u = (acc[q][rg][rh][i] + b4[q] - mu) * rs * gA[q] + bB[q];
          float g2 = 1.f / (1.f + __expf(-u));
          float ft = g2 * po[col] + bhalf(gio[q][rg][rh][i >> 1], i & 1);
          aT[rr * APITCH + col] = (short)f2bf(ft);
        }
      }
  __syncthreads();

  // ---- PH4: fc, LN, relu -> out ----
  loadA64(aT, a, lr, lh);
  gemm64(a, fcWf, acc, wv, lane);
#pragma unroll
  for (int q = 0; q < 4; q++) b4[q] = fcb[cb + q * 16 + lr];
  statsW64(acc, b4, sPP[0], qPP[0], wv, lr, lh);
  __syncthreads();
#pragma unroll
  for (int q = 0; q < 4; q++) { gA[q] = fng[cb + q * 16 + lr]; bB[q] = fnb[cb + q * 16 + lr]; }
#pragma unroll
  for (int rg = 0; rg < 2; rg++)
#pragma unroll
    for (int rh = 0; rh < 2; rh++)
#pragma unroll
      for (int i = 0; i < 4; i++) {
        const int rr = rg * 32 + rh * 16 + lh * 4 + i;
        float mu, rs;
        muRs(sPP[0], qPP[0], rr, mu, rs);
#pragma unroll
        for (int q = 0; q < 4; q++) {
          const int col = cb + q * 16 + lr;
          float v = (acc[q][rg][rh][i] + b4[q] - mu) * rs * gA[q] + bB[q];
          out[(size_t)(r0 + rr) * 256 + col] = fmaxf(v, 0.f);
        }
      }
}

// ================= ABLATION: R6 32-row structure, gemm removed =================
// fakeAcc derives acc from the staged a-frags (keeps staging+ds_read live),
// drops the 32 weight-loads + 64 MFMAs per phase. No global writes; results
// kept alive via asm. Measures "everything except the gemm inner core".

__device__ __forceinline__ void loadA2(const short* src, bf16x8 (&a)[2][8],
                                       int lr, int lh) {
#pragma unroll
  for (int kk = 0; kk < 8; kk++) {
    a[0][kk] = *(const bf16x8*)&src[lr * APITCH + kk * 32 + lh * 8];
    a[1][kk] = *(const bf16x8*)&src[(16 + lr) * APITCH + kk * 32 + lh * 8];
  }
}
__device__ __forceinline__ void fakeAcc(const bf16x8 (&a)[2][8], f32x4 (&acc)[4][2]) {
#pragma unroll
  for (int q = 0; q < 4; q++)
#pragma unroll
    for (int rh = 0; rh < 2; rh++)
#pragma unroll
      for (int i = 0; i < 4; i++)
        acc[q][rh][i] = bhalf(((const unsigned*)&a[rh][q])[i], i & 1);
}
__device__ __forceinline__ void statsW(const f32x4 (&acc)[4][2], const float (&b4)[4],
                                       float* sP, float* qP, int wv, int lr, int lh) {
#pragma unroll
  for (int rh = 0; rh < 2; rh++)
#pragma unroll
    for (int i = 0; i < 4; i++) {
      float s = 0.f, qq = 0.f;
#pragma unroll
      for (int q = 0; q < 4; q++) { float v = acc[q][rh][i] + b4[q]; s += v; qq += v * v; }
#pragma unroll
      for (int m = 1; m < 16; m <<= 1) { s += __shfl_xor(s, m); qq += __shfl_xor(qq, m); }
      if (lr == 0) {
        int r = rh * 16 + lh * 4 + i;
        sP[wv * 32 + r] = s; qP[wv * 32 + r] = qq;
      }
    }
}
__device__ __forceinline__ void statsR(const float* sP, const float* qP,
                                       float (&mu)[2][4], float (&rs)[2][4], int lh) {
#pragma unroll
  for (int rh = 0; rh < 2; rh++)
#pragma unroll
    for (int i = 0; i < 4; i++) {
      int r = rh * 16 + lh * 4 + i;
      float S = sP[r] + sP[32 + r] + sP[64 + r] + sP[96 + r];
      float Q = qP[r] + qP[32 + r] + qP[64 + r] + qP[96 + r];
      float m = S * (1.f / 256.f);
      mu[rh][i] = m;
      rs[rh][i] = rsqrtf(Q * (1.f / 256.f) - m * m + EPS);
    }
}

__global__ __launch_bounds__(256) void k_abl(
    const float* __restrict__ inf, const float* __restrict__ inpb,
    const float* __restrict__ igb, const float* __restrict__ ugb,
    const float* __restrict__ fcb,
    const float* __restrict__ nig, const float* __restrict__ nib,
    const float* __restrict__ iig, const float* __restrict__ iib,
    const float* __restrict__ iog, const float* __restrict__ iob,
    const float* __restrict__ fng, const float* __restrict__ fnb,
    const float* __restrict__ param_in, const float* __restrict__ param_out_ln) {
  __shared__ short aT[32 * APITCH];
  __shared__ short gT[32 * APITCH];
  __shared__ float sP[2][128], qP[2][128];

  const int t = threadIdx.x;
  const int wv = t >> 6, lane = t & 63, lr = lane & 15, lh = lane >> 4;
  const int cb = wv * 64;
  const int r0 = blockIdx.x * 32;

#pragma unroll
  for (int j = 0; j < 8; j++) {
    const int idx4 = j * 256 + t;
    const int row = idx4 >> 6;
    const int c4 = (idx4 & 63) << 2;
    const float4 v = *(const float4*)&inf[(size_t)(r0 + row) * 256 + c4];
    uint2 pk;
    pk.x = cvt_pk(v.x, v.y);
    pk.y = cvt_pk(v.z, v.w);
    *(uint2*)&aT[row * APITCH + c4] = pk;
  }
  __syncthreads();

  bf16x8 a[2][8];
  f32x4 acc[4][2];
  float b4[4], mu[2][4], rs[2][4], gA[4], bB[4];
  unsigned gio[4][2][2];

  loadA2(aT, a, lr, lh);

  // PH0 (no gemm)
  fakeAcc(a, acc);
#pragma unroll
  for (int q = 0; q < 4; q++) b4[q] = inpb[cb + q * 16 + lr];
#pragma unroll
  for (int rh = 0; rh < 2; rh++)
#pragma unroll
    for (int i = 0; i < 4; i++) {
      const int rr = rh * 16 + lh * 4 + i;
      const float* pin = param_in + (size_t)div9(r0 + rr) * 256;
#pragma unroll
      for (int q = 0; q < 4; q++) {
        const int col = cb + q * 16 + lr;
        float g = (acc[q][rh][i] + b4[q]) * pin[col];
        gT[rr * APITCH + col] = (short)f2bf(g);
      }
    }

  // PH1
  fakeAcc(a, acc);
#pragma unroll
  for (int q = 0; q < 4; q++) b4[q] = inpb[256 + cb + q * 16 + lr];
  statsW(acc, b4, sP[1], qP[1], wv, lr, lh);
  __syncthreads();
  statsR(sP[1], qP[1], mu, rs, lh);
#pragma unroll
  for (int q = 0; q < 4; q++) {
    const int col = cb + q * 16 + lr;
    const float ga = iog[col], be = iob[col];
#pragma unroll
    for (int rh = 0; rh < 2; rh++) {
      float v0 = (acc[q][rh][0] + b4[q] - mu[rh][0]) * rs[rh][0] * ga + be;
      float v1 = (acc[q][rh][1] + b4[q] - mu[rh][1]) * rs[rh][1] * ga + be;
      float v2 = (acc[q][rh][2] + b4[q] - mu[rh][2]) * rs[rh][2] * ga + be;
      float v3 = (acc[q][rh][3] + b4[q] - mu[rh][3]) * rs[rh][3] * ga + be;
      gio[q][rh][0] = cvt_pk(v0, v1);
      gio[q][rh][1] = cvt_pk(v2, v3);
    }
  }

  // PH2
  loadA2(gT, a, lr, lh);
  fakeAcc(a, acc);
#pragma unroll
  for (int q = 0; q < 4; q++) b4[q] = igb[cb + q * 16 + lr];
  statsW(acc, b4, sP[0], qP[0], wv, lr, lh);
  __syncthreads();
  statsR(sP[0], qP[0], mu, rs, lh);
#pragma unroll
  for (int q = 0; q < 4; q++) {
    const int col = cb + q * 16 + lr;
    const float ga = iig[col], be = iib[col];
#pragma unroll
    for (int rh = 0; rh < 2; rh++) {
      float v[4];
#pragma unroll
      for (int i = 0; i < 4; i++) {
        float p = (acc[q][rh][i] + b4[q] - mu[rh][i]) * rs[rh][i] * ga + be;
        float g1 = 1.f / (1.f + __expf(-p));
        v[i] = g1 * bhalf(gio[q][rh][i >> 1], i & 1);
      }
      gio[q][rh][0] = cvt_pk(v[0], v[1]);
      gio[q][rh][1] = cvt_pk(v[2], v[3]);
    }
  }

  // PH3
  fakeAcc(a, acc);
#pragma unroll
  for (int q = 0; q < 4; q++) b4[q] = ugb[cb + q * 16 + lr];
  statsW(acc, b4, sP[1], qP[1], wv, lr, lh);
  __syncthreads();
  statsR(sP[1], qP[1], mu, rs, lh);
#pragma unroll
  for (int q = 0; q < 4; q++) { gA[q] = nig[cb + q * 16 + lr]; bB[q] = nib[cb + q * 16 + lr]; }
#pragma unroll
  for (int rh = 0; rh < 2; rh++)
#pragma unroll
    for (int i = 0; i < 4; i++) {
      const int rr = rh * 16 + lh * 4 + i;
      const float* po = param_out_ln + (size_t)div9(r0 + rr) * 256;
#pragma unroll
      for (int q = 0; q < 4; q++) {
        const int col = cb + q * 16 + lr;
        float u = (acc[q][rh][i] + b4[q] - mu[rh][i]) * rs[rh][i] * gA[q] + bB[q];
        float g2 = 1.f / (1.f + __expf(-u));
        float ft = g2 * po[col] + bhalf(gio[q][rh][i >> 1], i & 1);
        aT[rr * APITCH + col] = (short)f2bf(ft);
      }
    }
  __syncthreads();

  // PH4
  loadA2(aT, a, lr, lh);
  fakeAcc(a, acc);
#pragma unroll
  for (int q = 0; q < 4; q++) b4[q] = fcb[cb + q * 16 + lr];
  statsW(acc, b4, sP[0], qP[0], wv, lr, lh);
  __syncthreads();
  statsR(sP[0], qP[0], mu, rs, lh);
#pragma unroll
  for (int q = 0; q < 4; q++) { gA[q] = fng[cb + q * 16 + lr]; bB[q] = fnb[cb + q * 16 + lr]; }
  float cs = 0.f;
#pragma unroll
  for (int q = 0; q < 4; q++)
#pragma unroll
    for (int rh = 0; rh < 2; rh++)
#pragma unroll
      for (int i = 0; i < 4; i++) {
        float v = (acc[q][rh][i] + b4[q] - mu[rh][i]) * rs[rh][i] * gA[q] + bB[q];
        cs += fmaxf(v, 0.f);
      }
  asm volatile("" :: "v"(cs));   // keepalive: no global write, no DCE
}

// ================= kernel 1: params (unchanged) =================
#define FPITCH 516

__device__ __forceinline__ void red8(float& s, float& q) {
#pragma unroll
  for (int m = 1; m < 8; m <<= 1) { s += __shfl_xor(s, m); q += __shfl_xor(q, m); }
}

__global__ __launch_bounds__(256) void k_params(
    const float* __restrict__ uf, const unsigned short* __restrict__ dynWf,
    const float* __restrict__ dynb, const float* __restrict__ nog,
    const float* __restrict__ nob, float* __restrict__ param_in,
    float* __restrict__ param_out_ln) {
  __shared__ short aT[32 * APITCH];
  __shared__ float fBuf[32 * FPITCH];
  const int t = threadIdx.x;
  const int wv = t >> 6, lane = t & 63, lr = lane & 15, lh = lane >> 4;
  const int r0 = blockIdx.x * 32;
#pragma unroll
  for (int j = 0; j < 8; j++) {
    const int idx4 = j * 256 + t;
    const int row = idx4 >> 6;
    const int c4 = (idx4 & 63) << 2;
    const float4 v = *(const float4*)&uf[(size_t)(r0 + row) * 256 + c4];
    uint2 pk;
    pk.x = cvt_pk(v.x, v.y);
    pk.y = cvt_pk(v.z, v.w);
    *(uint2*)&aT[row * APITCH + c4] = pk;
  }
  __syncthreads();
  bf16x8 a0[8], a1[8];
#pragma unroll
  for (int kk = 0; kk < 8; kk++) {
    a0[kk] = *(const bf16x8*)&aT[lr * APITCH + kk * 32 + lh * 8];
    a1[kk] = *(const bf16x8*)&aT[(16 + lr) * APITCH + kk * 32 + lh * 8];
  }
#pragma unroll 1
  for (int cp = 0; cp < 8; cp++) {
    const int ct = wv * 8 + cp;
    bf16x8 b[8];
#pragma unroll
    for (int kk = 0; kk < 8; kk++)
      b[kk] = *(const bf16x8*)&dynWf[((ct * 8 + kk) * 64 + lane) * 8];
    const float bi = dynb[ct * 16 + lr];
    f32x4 c0 = {0.f, 0.f, 0.f, 0.f}, c1 = c0;
#pragma unroll
    for (int kk = 0; kk < 8; kk++) {
      c0 = __builtin_amdgcn_mfma_f32_16x16x32_bf16(a0[kk], b[kk], c0, 0, 0, 0);
      c1 = __builtin_amdgcn_mfma_f32_16x16x32_bf16(a1[kk], b[kk], c1, 0, 0, 0);
    }
#pragma unroll
    for (int i = 0; i < 4; i++) {
      fBuf[(lh * 4 + i) * FPITCH + ct * 16 + lr] = c0[i] + bi;
      fBuf[(16 + lh * 4 + i) * FPITCH + ct * 16 + lr] = c1[i] + bi;
    }
  }
  __syncthreads();
  const int row = t >> 3, j = t & 7;
  float s = 0.f, q = 0.f;
#pragma unroll
  for (int i = 0; i < 32; i++) {
    float x = fBuf[row * FPITCH + 256 + j + 8 * i];
    s += x; q += x * x;
  }
  red8(s, q);
  const float mu = s * (1.f / 256.f);
  const float rsv = rsqrtf(q * (1.f / 256.f) - mu * mu + EPS);
#pragma unroll 1
  for (int i = 0; i < 32; i++) {
    const int c = j + 8 * i;
    float x = fBuf[row * FPITCH + 256 + c];
    param_out_ln[(size_t)(r0 + row) * 256 + c] = (x - mu) * rsv * nog[c] + nob[c];
  }
#pragma unroll
  for (int jj = 0; jj < 8; jj++) {
    const int idx4 = jj * 256 + t;
    const int rwq = idx4 >> 6;
    const int c4 = (idx4 & 63) << 2;
    float4 v;
    v.x = fBuf[rwq * FPITCH + c4 + 0];
    v.y = fBuf[rwq * FPITCH + c4 + 1];
    v.z = fBuf[rwq * FPITCH + c4 + 2];
    v.w = fBuf[rwq * FPITCH + c4 + 3];
    *(float4*)&param_in[(size_t)(r0 + rwq) * 256 + c4] = v;
  }
}

extern "C" void kernel_launch(void* const* d_in, const int* in_sizes, int n_in,
                              void* d_out, int out_size, void* d_ws, size_t ws_size,
                              hipStream_t stream) {
  const float* uf   = (const float*)d_in[0];
  const float* inf  = (const float*)d_in[1];
  const float* dynW = (const float*)d_in[2];
  const float* dynb = (const float*)d_in[3];
  const float* inpW = (const float*)d_in[4];
  const float* inpb = (const float*)d_in[5];
  const float* igW  = (const float*)d_in[6];
  const float* igb  = (const float*)d_in[7];
  const float* ugW  = (const float*)d_in[8];
  const float* ugb  = (const float*)d_in[9];
  const float* fcW  = (const float*)d_in[10];
  const float* fcb  = (const float*)d_in[11];
  const float* nig  = (const float*)d_in[12];
  const float* nib  = (const float*)d_in[13];
  const float* nog  = (const float*)d_in[14];
  const float* nob  = (const float*)d_in[15];
  const float* iig  = (const float*)d_in[16];
  const float* iib  = (const float*)d_in[17];
  const float* iog  = (const float*)d_in[18];
  const float* iob  = (const float*)d_in[19];
  const float* fng  = (const float*)d_in[20];
  const float* fnb  = (const float*)d_in[21];
  float* out = (float*)d_out;

  char* ws = (char*)d_ws;
  unsigned short* Wf = (unsigned short*)ws;
  unsigned short* dynWf = Wf;
  unsigned short* inpWf = Wf + 131072;
  unsigned short* igWf  = Wf + 262144;
  unsigned short* ugWf  = Wf + 327680;
  unsigned short* fcWf  = Wf + 393216;
  float* param_in     = (float*)(ws + (1 << 20));
  float* param_out_ln = (float*)(ws + (1 << 20) + (16 << 20));

  k_cvt_all<<<dim3(1792), dim3(256), 0, stream>>>(dynW, inpW, igW, ugW, fcW, Wf);

  k_params<<<dim3(512), dim3(256), 0, stream>>>(uf, dynWf, dynb, nog, nob,
                                                param_in, param_out_ln);

  k_main64<<<dim3(2304), dim3(256), 0, stream>>>(
      inf, inpWf, inpb, igWf, igb, ugWf, ugb, fcWf, fcb,
      nig, nib, iig, iib, iog, iob, fng, fnb,
      param_in, param_out_ln, out);

  // Ablation probe (diagnostic): R6 structure minus weight-loads+MFMA.
  k_abl<<<dim3(4608), dim3(256), 0, stream>>>(
      inf, inpb, igb, ugb, fcb, nig, nib, iig, iib, iog, iob, fng, fnb,
      param_in, param_out_ln);
}

// Round 8
// 385.592 us; speedup vs baseline: 1.3173x; 1.3173x over previous
//
#include <hip/hip_runtime.h>

#define EPS 1e-5f
#define APITCH 264   // bf16 tile row pitch (shorts)

typedef __attribute__((ext_vector_type(8))) short bf16x8;
typedef __attribute__((ext_vector_type(4))) float f32x4;

// RTNE (one-time weight conversion)
__device__ __forceinline__ unsigned short f2b_rtne(float f) {
  unsigned u = __builtin_bit_cast(unsigned, f);
  u += 0x7fffu + ((u >> 16) & 1u);
  return (unsigned short)(u >> 16);
}
// fast round-half-up bf16
__device__ __forceinline__ unsigned short f2bf(float f) {
  unsigned u = __builtin_bit_cast(unsigned, f);
  return (unsigned short)((u + 0x8000u) >> 16);
}
// HW packed f32->2xbf16 (RTNE)
__device__ __forceinline__ unsigned cvt_pk(float lo, float hi) {
  unsigned r;
  asm("v_cvt_pk_bf16_f32 %0, %1, %2" : "=v"(r) : "v"(lo), "v"(hi));
  return r;
}
__device__ __forceinline__ float bhalf(unsigned pk, int hi) {
  unsigned u = hi ? (pk & 0xffff0000u) : (pk << 16);
  return __builtin_bit_cast(float, u);
}
__device__ __forceinline__ int div9(int r) {
  return (int)(__umulhi((unsigned)r, 954437177u) >> 1);
}

// Convert all 5 weight matrices into MFMA-fragment-linear bf16 (contiguous dst).
__global__ void k_cvt_all(const float* __restrict__ dynW, const float* __restrict__ inpW,
                          const float* __restrict__ igW, const float* __restrict__ ugW,
                          const float* __restrict__ fcW, unsigned short* __restrict__ dst) {
  int i = blockIdx.x * blockDim.x + threadIdx.x;   // [0, 458752)
  const float* src; int off;
  if (i < 131072)      { src = dynW; off = i; }
  else if (i < 262144) { src = inpW; off = i - 131072; }
  else if (i < 327680) { src = igW;  off = i - 262144; }
  else if (i < 393216) { src = ugW;  off = i - 327680; }
  else                 { src = fcW;  off = i - 393216; }
  int j = off & 7, lane = (off >> 3) & 63, kk = (off >> 9) & 7, ct = off >> 12;
  int row = ct * 16 + (lane & 15);
  int col = kk * 32 + (lane >> 4) * 8 + j;
  dst[i] = f2b_rtne(src[row * 256 + col]);
}

// ================= 64-row main kernel, b-pipelined =================

__device__ __forceinline__ void loadA64(const short* src, bf16x8 (&a)[2][2][8],
                                        int lr, int lh) {
#pragma unroll
  for (int rg = 0; rg < 2; rg++)
#pragma unroll
    for (int rh = 0; rh < 2; rh++)
#pragma unroll
      for (int kk = 0; kk < 8; kk++)
        a[rg][rh][kk] = *(const bf16x8*)&src[(rg * 32 + rh * 16 + lr) * APITCH + kk * 32 + lh * 8];
}

__device__ __forceinline__ void ldB(const unsigned short* __restrict__ Wp, bf16x8 (&b)[8]) {
#pragma unroll
  for (int kk = 0; kk < 8; kk++) b[kk] = *(const bf16x8*)&Wp[kk * 512];
}

// 16 col-outputs (one q tile) over 64 rows: 32 MFMAs, q compile-time const
__device__ __forceinline__ void mfma16(const bf16x8 (&a)[2][2][8], const bf16x8 (&b)[8],
                                       f32x4 (&acc)[4][2][2], int q) {
#pragma unroll
  for (int rg = 0; rg < 2; rg++)
#pragma unroll
    for (int rh = 0; rh < 2; rh++) {
      acc[q][rg][rh] = (f32x4){0.f, 0.f, 0.f, 0.f};
#pragma unroll
      for (int kk = 0; kk < 8; kk++)
        acc[q][rg][rh] = __builtin_amdgcn_mfma_f32_16x16x32_bf16(
            a[rg][rh][kk], b[kk], acc[q][rg][rh], 0, 0, 0);
    }
}

// One phase with b double-buffer. Precondition: bA holds this phase's q0 frags.
// Postcondition: bA holds Wnext's q0 frags (prefetched under this phase's MFMAs).
__device__ __forceinline__ void gemmPhase(const bf16x8 (&a)[2][2][8],
    const unsigned short* __restrict__ W, const unsigned short* __restrict__ Wnext,
    f32x4 (&acc)[4][2][2], bf16x8 (&bA)[8], bf16x8 (&bB)[8], int wv, int lane) {
  ldB(W + ((wv * 4 + 1) << 12) + lane * 8, bB); mfma16(a, bA, acc, 0);
  ldB(W + ((wv * 4 + 2) << 12) + lane * 8, bA); mfma16(a, bB, acc, 1);
  ldB(W + ((wv * 4 + 3) << 12) + lane * 8, bB); mfma16(a, bA, acc, 2);
  ldB(Wnext + ((wv * 4 + 0) << 12) + lane * 8, bA); mfma16(a, bB, acc, 3);
}

__device__ __forceinline__ void statsW64(const f32x4 (&acc)[4][2][2], const float (&b4)[4],
                                         float* sP, float* qP, int wv, int lr, int lh) {
#pragma unroll
  for (int rg = 0; rg < 2; rg++)
#pragma unroll
    for (int rh = 0; rh < 2; rh++)
#pragma unroll
      for (int i = 0; i < 4; i++) {
        float s = 0.f, qq = 0.f;
#pragma unroll
        for (int q = 0; q < 4; q++) { float v = acc[q][rg][rh][i] + b4[q]; s += v; qq += v * v; }
#pragma unroll
        for (int m = 1; m < 16; m <<= 1) { s += __shfl_xor(s, m); qq += __shfl_xor(qq, m); }
        if (lr == 0) {
          int rr = rg * 32 + rh * 16 + lh * 4 + i;
          sP[wv * 64 + rr] = s; qP[wv * 64 + rr] = qq;
        }
      }
}
__device__ __forceinline__ void muRs(const float* sP, const float* qP, int rr,
                                     float& mu, float& rs) {
  float S = sP[rr] + sP[64 + rr] + sP[128 + rr] + sP[192 + rr];
  float Q = qP[rr] + qP[64 + rr] + qP[128 + rr] + qP[192 + rr];
  mu = S * (1.f / 256.f);
  rs = rsqrtf(Q * (1.f / 256.f) - mu * mu + EPS);
}

// NOTE: no min-waves arg — a second __launch_bounds__ argument halves usable
// arch-VGPR on MFMA kernels (observed cap = 256/minwaves, R2-R4) and forces scratch.
__global__ __launch_bounds__(256) void k_main64(
    const float* __restrict__ inf,
    const unsigned short* __restrict__ inpWf, const float* __restrict__ inpb,
    const unsigned short* __restrict__ igWf, const float* __restrict__ igb,
    const unsigned short* __restrict__ ugWf, const float* __restrict__ ugb,
    const unsigned short* __restrict__ fcWf, const float* __restrict__ fcb,
    const float* __restrict__ nig, const float* __restrict__ nib,
    const float* __restrict__ iig, const float* __restrict__ iib,
    const float* __restrict__ iog, const float* __restrict__ iob,
    const float* __restrict__ fng, const float* __restrict__ fnb,
    const float* __restrict__ param_in, const float* __restrict__ param_out_ln,
    float* __restrict__ out) {
  __shared__ short aT[64 * APITCH];
  __shared__ short gT[64 * APITCH];
  __shared__ float sPP[2][256], qPP[2][256];

  const int t = threadIdx.x;
  const int wv = t >> 6, lane = t & 63, lr = lane & 15, lh = lane >> 4;
  const int cb = wv * 64;
  const int r0 = blockIdx.x * 64;

  // stage 64x256 f32 -> bf16 LDS
#pragma unroll
  for (int j = 0; j < 16; j++) {
    const int idx4 = j * 256 + t;
    const int row = idx4 >> 6;
    const int c4 = (idx4 & 63) << 2;
    const float4 v = *(const float4*)&inf[(size_t)(r0 + row) * 256 + c4];
    uint2 pk;
    pk.x = cvt_pk(v.x, v.y);
    pk.y = cvt_pk(v.z, v.w);
    *(uint2*)&aT[row * APITCH + c4] = pk;
  }
  __syncthreads();

  bf16x8 a[2][2][8];
  bf16x8 bA[8], bB[8];
  f32x4 acc[4][2][2];
  float b4[4], gA[4], bB4[4];
  unsigned gio[4][2][2][2];

  // prologue: issue PH0 q0 weight loads first (longest latency), then LDS A-reads
  ldB(inpWf + ((wv * 4) << 12) + lane * 8, bA);
  loadA64(aT, a, lr, lh);

  // ---- PH0: input_in -> gate_feats -> gT (prefetches PH1 q0) ----
  gemmPhase(a, inpWf, inpWf + (16 << 12), acc, bA, bB, wv, lane);
#pragma unroll
  for (int q = 0; q < 4; q++) b4[q] = inpb[cb + q * 16 + lr];
#pragma unroll
  for (int rg = 0; rg < 2; rg++)
#pragma unroll
    for (int rh = 0; rh < 2; rh++)
#pragma unroll
      for (int i = 0; i < 4; i++) {
        const int rr = rg * 32 + rh * 16 + lh * 4 + i;
        const float* pin = param_in + (size_t)div9(r0 + rr) * 256;
#pragma unroll
        for (int q = 0; q < 4; q++) {
          const int col = cb + q * 16 + lr;
          float g = (acc[q][rg][rh][i] + b4[q]) * pin[col];
          gT[rr * APITCH + col] = (short)f2bf(g);
        }
      }

  // ---- PH1: input_out, LN -> gio (prefetches PH2 q0) ----
  gemmPhase(a, inpWf + (16 << 12), igWf, acc, bA, bB, wv, lane);
#pragma unroll
  for (int q = 0; q < 4; q++) b4[q] = inpb[256 + cb + q * 16 + lr];
  statsW64(acc, b4, sPP[1], qPP[1], wv, lr, lh);
  __syncthreads();   // also publishes gT for PH2
#pragma unroll
  for (int q = 0; q < 4; q++) { gA[q] = iog[cb + q * 16 + lr]; bB4[q] = iob[cb + q * 16 + lr]; }
#pragma unroll
  for (int rg = 0; rg < 2; rg++)
#pragma unroll
    for (int rh = 0; rh < 2; rh++) {
      float vv[4][4];
#pragma unroll
      for (int i = 0; i < 4; i++) {
        const int rr = rg * 32 + rh * 16 + lh * 4 + i;
        float mu, rs;
        muRs(sPP[1], qPP[1], rr, mu, rs);
#pragma unroll
        for (int q = 0; q < 4; q++)
          vv[q][i] = (acc[q][rg][rh][i] + b4[q] - mu) * rs * gA[q] + bB4[q];
      }
#pragma unroll
      for (int q = 0; q < 4; q++) {
        gio[q][rg][rh][0] = cvt_pk(vv[q][0], vv[q][1]);
        gio[q][rg][rh][1] = cvt_pk(vv[q][2], vv[q][3]);
      }
    }

  // ---- PH2: ig gate on gate_feats; gio <- g1 * ioLN (prefetches PH3 q0) ----
  loadA64(gT, a, lr, lh);
  gemmPhase(a, igWf, ugWf, acc, bA, bB, wv, lane);
#pragma unroll
  for (int q = 0; q < 4; q++) b4[q] = igb[cb + q * 16 + lr];
  statsW64(acc, b4, sPP[0], qPP[0], wv, lr, lh);
  __syncthreads();
#pragma unroll
  for (int q = 0; q < 4; q++) { gA[q] = iig[cb + q * 16 + lr]; bB4[q] = iib[cb + q * 16 + lr]; }
#pragma unroll
  for (int rg = 0; rg < 2; rg++)
#pragma unroll
    for (int rh = 0; rh < 2; rh++) {
      float vv[4][4];
#pragma unroll
      for (int i = 0; i < 4; i++) {
        const int rr = rg * 32 + rh * 16 + lh * 4 + i;
        float mu, rs;
        muRs(sPP[0], qPP[0], rr, mu, rs);
#pragma unroll
        for (int q = 0; q < 4; q++) {
          float p = (acc[q][rg][rh][i] + b4[q] - mu) * rs * gA[q] + bB4[q];
          float g1 = 1.f / (1.f + __expf(-p));
          vv[q][i] = g1 * bhalf(gio[q][rg][rh][i >> 1], i & 1);
        }
      }
#pragma unroll
      for (int q = 0; q < 4; q++) {
        gio[q][rg][rh][0] = cvt_pk(vv[q][0], vv[q][1]);
        gio[q][rg][rh][1] = cvt_pk(vv[q][2], vv[q][3]);
      }
    }

  // ---- PH3: ug gate; features -> aT (prefetches PH4 q0) ----
  gemmPhase(a, ugWf, fcWf, acc, bA, bB, wv, lane);
#pragma unroll
  for (int q = 0; q < 4; q++) b4[q] = ugb[cb + q * 16 + lr];
  statsW64(acc, b4, sPP[1], qPP[1], wv, lr, lh);
  __syncthreads();
#pragma unroll
  for (int q = 0; q < 4; q++) { gA[q] = nig[cb + q * 16 + lr]; bB4[q] = nib[cb + q * 16 + lr]; }
#pragma unroll
  for (int rg = 0; rg < 2; rg++)
#pragma unroll
    for (int rh = 0; rh < 2; rh++)
#pragma unroll
      for (int i = 0; i < 4; i++) {
        const int rr = rg * 32 + rh * 16 + lh * 4 + i;
        float mu, rs;
        muRs(sPP[1], qPP[1], rr, mu, rs);
        const float* po = param_out_ln + (size_t)div9(r0 + rr) * 256;
#pragma unroll
        for (int q = 0; q < 4; q++) {
          const int col = cb + q * 16 + lr;
          float u = (acc[q][rg][rh][i] + b4[q] - mu) * rs * gA[q] + bB4[q];
          float g2 = 1.f / (1.f + __expf(-u));
          float ft = g2 * po[col] + bhalf(gio[q][rg][rh][i >> 1], i & 1);
          aT[rr * APITCH + col] = (short)f2bf(ft);
        }
      }
  __syncthreads();   // aT(features) ready

  // ---- PH4: fc, LN, relu -> out (dummy next-prefetch is DCE'd) ----
  loadA64(aT, a, lr, lh);
  gemmPhase(a, fcWf, fcWf, acc, bA, bB, wv, lane);
#pragma unroll
  for (int q = 0; q < 4; q++) b4[q] = fcb[cb + q * 16 + lr];
  statsW64(acc, b4, sPP[0], qPP[0], wv, lr, lh);
  __syncthreads();
#pragma unroll
  for (int q = 0; q < 4; q++) { gA[q] = fng[cb + q * 16 + lr]; bB4[q] = fnb[cb + q * 16 + lr]; }
#pragma unroll
  for (int rg = 0; rg < 2; rg++)
#pragma unroll
    for (int rh = 0; rh < 2; rh++)
#pragma unroll
      for (int i = 0; i < 4; i++) {
        const int rr = rg * 32 + rh * 16 + lh * 4 + i;
        float mu, rs;
        muRs(sPP[0], qPP[0], rr, mu, rs);
#pragma unroll
        for (int q = 0; q < 4; q++) {
          const int col = cb + q * 16 + lr;
          float v = (acc[q][rg][rh][i] + b4[q] - mu) * rs * gA[q] + bB4[q];
          out[(size_t)(r0 + rr) * 256 + col] = fmaxf(v, 0.f);
        }
      }
}

// ================= kernel 1: params (unchanged) =================
#define FPITCH 516

__device__ __forceinline__ void red8(float& s, float& q) {
#pragma unroll
  for (int m = 1; m < 8; m <<= 1) { s += __shfl_xor(s, m); q += __shfl_xor(q, m); }
}

__global__ __launch_bounds__(256) void k_params(
    const float* __restrict__ uf, const unsigned short* __restrict__ dynWf,
    const float* __restrict__ dynb, const float* __restrict__ nog,
    const float* __restrict__ nob, float* __restrict__ param_in,
    float* __restrict__ param_out_ln) {
  __shared__ short aT[32 * APITCH];
  __shared__ float fBuf[32 * FPITCH];
  const int t = threadIdx.x;
  const int wv = t >> 6, lane = t & 63, lr = lane & 15, lh = lane >> 4;
  const int r0 = blockIdx.x * 32;
#pragma unroll
  for (int j = 0; j < 8; j++) {
    const int idx4 = j * 256 + t;
    const int row = idx4 >> 6;
    const int c4 = (idx4 & 63) << 2;
    const float4 v = *(const float4*)&uf[(size_t)(r0 + row) * 256 + c4];
    uint2 pk;
    pk.x = cvt_pk(v.x, v.y);
    pk.y = cvt_pk(v.z, v.w);
    *(uint2*)&aT[row * APITCH + c4] = pk;
  }
  __syncthreads();
  bf16x8 a0[8], a1[8];
#pragma unroll
  for (int kk = 0; kk < 8; kk++) {
    a0[kk] = *(const bf16x8*)&aT[lr * APITCH + kk * 32 + lh * 8];
    a1[kk] = *(const bf16x8*)&aT[(16 + lr) * APITCH + kk * 32 + lh * 8];
  }
#pragma unroll 1
  for (int cp = 0; cp < 8; cp++) {
    const int ct = wv * 8 + cp;
    bf16x8 b[8];
#pragma unroll
    for (int kk = 0; kk < 8; kk++)
      b[kk] = *(const bf16x8*)&dynWf[((ct * 8 + kk) * 64 + lane) * 8];
    const float bi = dynb[ct * 16 + lr];
    f32x4 c0 = {0.f, 0.f, 0.f, 0.f}, c1 = c0;
#pragma unroll
    for (int kk = 0; kk < 8; kk++) {
      c0 = __builtin_amdgcn_mfma_f32_16x16x32_bf16(a0[kk], b[kk], c0, 0, 0, 0);
      c1 = __builtin_amdgcn_mfma_f32_16x16x32_bf16(a1[kk], b[kk], c1, 0, 0, 0);
    }
#pragma unroll
    for (int i = 0; i < 4; i++) {
      fBuf[(lh * 4 + i) * FPITCH + ct * 16 + lr] = c0[i] + bi;
      fBuf[(16 + lh * 4 + i) * FPITCH + ct * 16 + lr] = c1[i] + bi;
    }
  }
  __syncthreads();
  const int row = t >> 3, j = t & 7;
  float s = 0.f, q = 0.f;
#pragma unroll
  for (int i = 0; i < 32; i++) {
    float x = fBuf[row * FPITCH + 256 + j + 8 * i];
    s += x; q += x * x;
  }
  red8(s, q);
  const float mu = s * (1.f / 256.f);
  const float rsv = rsqrtf(q * (1.f / 256.f) - mu * mu + EPS);
#pragma unroll 1
  for (int i = 0; i < 32; i++) {
    const int c = j + 8 * i;
    float x = fBuf[row * FPITCH + 256 + c];
    param_out_ln[(size_t)(r0 + row) * 256 + c] = (x - mu) * rsv * nog[c] + nob[c];
  }
#pragma unroll
  for (int jj = 0; jj < 8; jj++) {
    const int idx4 = jj * 256 + t;
    const int rwq = idx4 >> 6;
    const int c4 = (idx4 & 63) << 2;
    float4 v;
    v.x = fBuf[rwq * FPITCH + c4 + 0];
    v.y = fBuf[rwq * FPITCH + c4 + 1];
    v.z = fBuf[rwq * FPITCH + c4 + 2];
    v.w = fBuf[rwq * FPITCH + c4 + 3];
    *(float4*)&param_in[(size_t)(r0 + rwq) * 256 + c4] = v;
  }
}

extern "C" void kernel_launch(void* const* d_in, const int* in_sizes, int n_in,
                              void* d_out, int out_size, void* d_ws, size_t ws_size,
                              hipStream_t stream) {
  const float* uf   = (const float*)d_in[0];
  const float* inf  = (const float*)d_in[1];
  const float* dynW = (const float*)d_in[2];
  const float* dynb = (const float*)d_in[3];
  const float* inpW = (const float*)d_in[4];
  const float* inpb = (const float*)d_in[5];
  const float* igW  = (const float*)d_in[6];
  const float* igb  = (const float*)d_in[7];
  const float* ugW  = (const float*)d_in[8];
  const float* ugb  = (const float*)d_in[9];
  const float* fcW  = (const float*)d_in[10];
  const float* fcb  = (const float*)d_in[11];
  const float* nig  = (const float*)d_in[12];
  const float* nib  = (const float*)d_in[13];
  const float* nog  = (const float*)d_in[14];
  const float* nob  = (const float*)d_in[15];
  const float* iig  = (const float*)d_in[16];
  const float* iib  = (const float*)d_in[17];
  const float* iog  = (const float*)d_in[18];
  const float* iob  = (const float*)d_in[19];
  const float* fng  = (const float*)d_in[20];
  const float* fnb  = (const float*)d_in[21];
  float* out = (float*)d_out;

  char* ws = (char*)d_ws;
  unsigned short* Wf = (unsigned short*)ws;
  unsigned short* dynWf = Wf;
  unsigned short* inpWf = Wf + 131072;
  unsigned short* igWf  = Wf + 262144;
  unsigned short* ugWf  = Wf + 327680;
  unsigned short* fcWf  = Wf + 393216;
  float* param_in     = (float*)(ws + (1 << 20));
  float* param_out_ln = (float*)(ws + (1 << 20) + (16 << 20));

  k_cvt_all<<<dim3(1792), dim3(256), 0, stream>>>(dynW, inpW, igW, ugW, fcW, Wf);

  k_params<<<dim3(512), dim3(256), 0, stream>>>(uf, dynWf, dynb, nog, nob,
                                                param_in, param_out_ln);

  k_main64<<<dim3(2304), dim3(256), 0, stream>>>(
      inf, inpWf, inpb, igWf, igb, ugWf, ugb, fcWf, fcb,
      nig, nib, iig, iib, iog, iob, fng, fnb,
      param_in, param_out_ln, out);
}

// Round 9
// 277.653 us; speedup vs baseline: 1.8294x; 1.3888x over previous
//
#include <hip/hip_runtime.h>

#define EPS 1e-5f
#define APITCH 264   // bf16 tile row pitch (shorts)

typedef __attribute__((ext_vector_type(8))) short bf16x8;
typedef __attribute__((ext_vector_type(4))) float f32x4;

// RTNE (one-time weight conversion)
__device__ __forceinline__ unsigned short f2b_rtne(float f) {
  unsigned u = __builtin_bit_cast(unsigned, f);
  u += 0x7fffu + ((u >> 16) & 1u);
  return (unsigned short)(u >> 16);
}
// fast round-half-up bf16
__device__ __forceinline__ unsigned short f2bf(float f) {
  unsigned u = __builtin_bit_cast(unsigned, f);
  return (unsigned short)((u + 0x8000u) >> 16);
}
// HW packed f32->2xbf16 (RTNE)
__device__ __forceinline__ unsigned cvt_pk(float lo, float hi) {
  unsigned r;
  asm("v_cvt_pk_bf16_f32 %0, %1, %2" : "=v"(r) : "v"(lo), "v"(hi));
  return r;
}
__device__ __forceinline__ float bhalf(unsigned pk, int hi) {
  unsigned u = hi ? (pk & 0xffff0000u) : (pk << 16);
  return __builtin_bit_cast(float, u);
}
__device__ __forceinline__ int div9(int r) {
  return (int)(__umulhi((unsigned)r, 954437177u) >> 1);
}

// Convert all 5 weight matrices into MFMA-fragment-linear bf16 (contiguous dst).
__global__ void k_cvt_all(const float* __restrict__ dynW, const float* __restrict__ inpW,
                          const float* __restrict__ igW, const float* __restrict__ ugW,
                          const float* __restrict__ fcW, unsigned short* __restrict__ dst) {
  int i = blockIdx.x * blockDim.x + threadIdx.x;   // [0, 458752)
  const float* src; int off;
  if (i < 131072)      { src = dynW; off = i; }
  else if (i < 262144) { src = inpW; off = i - 131072; }
  else if (i < 327680) { src = igW;  off = i - 262144; }
  else if (i < 393216) { src = ugW;  off = i - 327680; }
  else                 { src = fcW;  off = i - 393216; }
  int j = off & 7, lane = (off >> 3) & 63, kk = (off >> 9) & 7, ct = off >> 12;
  int row = ct * 16 + (lane & 15);
  int col = kk * 32 + (lane >> 4) * 8 + j;
  dst[i] = f2b_rtne(src[row * 256 + col]);
}

// ================= 32-row main kernel, register-diet (target <=128 total) =================
// Register budget rationale (occupancy tiers at VGPR ~64/128/256, unified VGPR+AGPR):
//   a[8]=32 (re-read from LDS per q, CSE-defeated) + b[8]=32 + acc[4][2]=32 + gio=16
//   + misc ~15  ->  ~125 total  ->  4 waves/SIMD with 4 blocks/CU (LDS 35.8KB).

// GEMM 32 rows x 64 cols; per q: 8 global b-loads, 16 LDS a-reads, 16 MFMA.
__device__ __forceinline__ void gemmQ(const short* src,
                                      const unsigned short* __restrict__ W,
                                      f32x4 (&acc)[4][2],
                                      int wv, int lane, int lr, int lh) {
#pragma unroll
  for (int q = 0; q < 4; q++) {
    const unsigned short* Wp = W + ((wv * 4 + q) << 12) + lane * 8;
    bf16x8 b[8];
#pragma unroll
    for (int kk = 0; kk < 8; kk++) b[kk] = *(const bf16x8*)&Wp[kk * 512];
    int zoff = 0;
    asm volatile("" : "+v"(zoff));          // opaque 0: forces a re-read each q
    const short* ap = src + zoff;
    bf16x8 a[8];
#pragma unroll
    for (int kk = 0; kk < 8; kk++)
      a[kk] = *(const bf16x8*)&ap[lr * APITCH + kk * 32 + lh * 8];
    acc[q][0] = (f32x4){0.f, 0.f, 0.f, 0.f};
#pragma unroll
    for (int kk = 0; kk < 8; kk++)
      acc[q][0] = __builtin_amdgcn_mfma_f32_16x16x32_bf16(a[kk], b[kk], acc[q][0], 0, 0, 0);
#pragma unroll
    for (int kk = 0; kk < 8; kk++)
      a[kk] = *(const bf16x8*)&ap[(16 + lr) * APITCH + kk * 32 + lh * 8];
    acc[q][1] = (f32x4){0.f, 0.f, 0.f, 0.f};
#pragma unroll
    for (int kk = 0; kk < 8; kk++)
      acc[q][1] = __builtin_amdgcn_mfma_f32_16x16x32_bf16(a[kk], b[kk], acc[q][1], 0, 0, 0);
  }
}

__device__ __forceinline__ void statsW(const f32x4 (&acc)[4][2], const float (&b4)[4],
                                       float* sP, float* qP, int wv, int lr, int lh) {
#pragma unroll
  for (int rh = 0; rh < 2; rh++)
#pragma unroll
    for (int i = 0; i < 4; i++) {
      float s = 0.f, qq = 0.f;
#pragma unroll
      for (int q = 0; q < 4; q++) { float v = acc[q][rh][i] + b4[q]; s += v; qq += v * v; }
#pragma unroll
      for (int m = 1; m < 16; m <<= 1) { s += __shfl_xor(s, m); qq += __shfl_xor(qq, m); }
      if (lr == 0) {
        int r = rh * 16 + lh * 4 + i;
        sP[wv * 32 + r] = s; qP[wv * 32 + r] = qq;
      }
    }
}
__device__ __forceinline__ void statsR(const float* sP, const float* qP,
                                       float (&mu)[2][4], float (&rs)[2][4], int lh) {
#pragma unroll
  for (int rh = 0; rh < 2; rh++)
#pragma unroll
    for (int i = 0; i < 4; i++) {
      int r = rh * 16 + lh * 4 + i;
      float S = sP[r] + sP[32 + r] + sP[64 + r] + sP[96 + r];
      float Q = qP[r] + qP[32 + r] + qP[64 + r] + qP[96 + r];
      float m = S * (1.f / 256.f);
      mu[rh][i] = m;
      rs[rh][i] = rsqrtf(Q * (1.f / 256.f) - m * m + EPS);
    }
}

// NOTE: no min-waves arg — a second __launch_bounds__ argument caps arch-VGPR at
// 256/minwaves on MFMA kernels (observed R2-R4) and forces scratch.
__global__ __launch_bounds__(256) void k_main(
    const float* __restrict__ inf,
    const unsigned short* __restrict__ inpWf, const float* __restrict__ inpb,
    const unsigned short* __restrict__ igWf, const float* __restrict__ igb,
    const unsigned short* __restrict__ ugWf, const float* __restrict__ ugb,
    const unsigned short* __restrict__ fcWf, const float* __restrict__ fcb,
    const float* __restrict__ nig, const float* __restrict__ nib,
    const float* __restrict__ iig, const float* __restrict__ iib,
    const float* __restrict__ iog, const float* __restrict__ iob,
    const float* __restrict__ fng, const float* __restrict__ fnb,
    const float* __restrict__ param_in, const float* __restrict__ param_out_ln,
    float* __restrict__ out) {
  __shared__ short aT[32 * APITCH];
  __shared__ short gT[32 * APITCH];
  __shared__ float sP[2][128], qP[2][128];

  const int t = threadIdx.x;
  const int wv = t >> 6, lane = t & 63, lr = lane & 15, lh = lane >> 4;
  const int cb = wv * 64;
  const int r0 = blockIdx.x * 32;

  // stage 32x256 f32 -> bf16 LDS (coalesced float4 in, packed b64 out)
#pragma unroll
  for (int j = 0; j < 8; j++) {
    const int idx4 = j * 256 + t;
    const int row = idx4 >> 6;
    const int c4 = (idx4 & 63) << 2;
    const float4 v = *(const float4*)&inf[(size_t)(r0 + row) * 256 + c4];
    uint2 pk;
    pk.x = cvt_pk(v.x, v.y);
    pk.y = cvt_pk(v.z, v.w);
    *(uint2*)&aT[row * APITCH + c4] = pk;
  }
  __syncthreads();

  f32x4 acc[4][2];
  float b4[4], mu[2][4], rs[2][4], gA[4], bB4[4];
  unsigned gio[4][2][2];   // packed bf16 pairs per (q, rh)

  // ---- PH0: input_in -> gate_feats -> gT ----
  gemmQ(aT, inpWf, acc, wv, lane, lr, lh);
#pragma unroll
  for (int q = 0; q < 4; q++) b4[q] = inpb[cb + q * 16 + lr];
#pragma unroll
  for (int rh = 0; rh < 2; rh++)
#pragma unroll
    for (int i = 0; i < 4; i++) {
      const int rr = rh * 16 + lh * 4 + i;
      const float* pin = param_in + (size_t)div9(r0 + rr) * 256;
#pragma unroll
      for (int q = 0; q < 4; q++) {
        const int col = cb + q * 16 + lr;
        float g = (acc[q][rh][i] + b4[q]) * pin[col];
        gT[rr * APITCH + col] = (short)f2bf(g);
      }
    }

  // ---- PH1: input_out, LN -> gio (ioLN packed) ----
  gemmQ(aT, inpWf + (16 << 12), acc, wv, lane, lr, lh);
#pragma unroll
  for (int q = 0; q < 4; q++) b4[q] = inpb[256 + cb + q * 16 + lr];
  statsW(acc, b4, sP[1], qP[1], wv, lr, lh);
  __syncthreads();   // publishes gT + stats
  statsR(sP[1], qP[1], mu, rs, lh);
#pragma unroll
  for (int q = 0; q < 4; q++) { gA[q] = iog[cb + q * 16 + lr]; bB4[q] = iob[cb + q * 16 + lr]; }
#pragma unroll
  for (int q = 0; q < 4; q++) {
#pragma unroll
    for (int rh = 0; rh < 2; rh++) {
      float v0 = (acc[q][rh][0] + b4[q] - mu[rh][0]) * rs[rh][0] * gA[q] + bB4[q];
      float v1 = (acc[q][rh][1] + b4[q] - mu[rh][1]) * rs[rh][1] * gA[q] + bB4[q];
      float v2 = (acc[q][rh][2] + b4[q] - mu[rh][2]) * rs[rh][2] * gA[q] + bB4[q];
      float v3 = (acc[q][rh][3] + b4[q] - mu[rh][3]) * rs[rh][3] * gA[q] + bB4[q];
      gio[q][rh][0] = cvt_pk(v0, v1);
      gio[q][rh][1] = cvt_pk(v2, v3);
    }
  }

  // ---- PH2: ig gate on gate_feats; gio <- g1 * ioLN ----
  gemmQ(gT, igWf, acc, wv, lane, lr, lh);
#pragma unroll
  for (int q = 0; q < 4; q++) b4[q] = igb[cb + q * 16 + lr];
  statsW(acc, b4, sP[0], qP[0], wv, lr, lh);
  __syncthreads();
  statsR(sP[0], qP[0], mu, rs, lh);
#pragma unroll
  for (int q = 0; q < 4; q++) { gA[q] = iig[cb + q * 16 + lr]; bB4[q] = iib[cb + q * 16 + lr]; }
#pragma unroll
  for (int q = 0; q < 4; q++) {
#pragma unroll
    for (int rh = 0; rh < 2; rh++) {
      float v[4];
#pragma unroll
      for (int i = 0; i < 4; i++) {
        float p = (acc[q][rh][i] + b4[q] - mu[rh][i]) * rs[rh][i] * gA[q] + bB4[q];
        float g1 = 1.f / (1.f + __expf(-p));
        v[i] = g1 * bhalf(gio[q][rh][i >> 1], i & 1);
      }
      gio[q][rh][0] = cvt_pk(v[0], v[1]);
      gio[q][rh][1] = cvt_pk(v[2], v[3]);
    }
  }

  // ---- PH3: ug gate; features = g2*param_out_ln + gio -> aT ----
  gemmQ(gT, ugWf, acc, wv, lane, lr, lh);
#pragma unroll
  for (int q = 0; q < 4; q++) b4[q] = ugb[cb + q * 16 + lr];
  statsW(acc, b4, sP[1], qP[1], wv, lr, lh);
  __syncthreads();
  statsR(sP[1], qP[1], mu, rs, lh);
#pragma unroll
  for (int q = 0; q < 4; q++) { gA[q] = nig[cb + q * 16 + lr]; bB4[q] = nib[cb + q * 16 + lr]; }
#pragma unroll
  for (int rh = 0; rh < 2; rh++)
#pragma unroll
    for (int i = 0; i < 4; i++) {
      const int rr = rh * 16 + lh * 4 + i;
      const float* po = param_out_ln + (size_t)div9(r0 + rr) * 256;
#pragma unroll
      for (int q = 0; q < 4; q++) {
        const int col = cb + q * 16 + lr;
        float u = (acc[q][rh][i] + b4[q] - mu[rh][i]) * rs[rh][i] * gA[q] + bB4[q];
        float g2 = 1.f / (1.f + __expf(-u));
        float ft = g2 * po[col] + bhalf(gio[q][rh][i >> 1], i & 1);
        aT[rr * APITCH + col] = (short)f2bf(ft);
      }
    }
  __syncthreads();   // aT(features) ready

  // ---- PH4: fc, LN, relu -> out ----
  gemmQ(aT, fcWf, acc, wv, lane, lr, lh);
#pragma unroll
  for (int q = 0; q < 4; q++) b4[q] = fcb[cb + q * 16 + lr];
  statsW(acc, b4, sP[0], qP[0], wv, lr, lh);
  __syncthreads();
  statsR(sP[0], qP[0], mu, rs, lh);
#pragma unroll
  for (int q = 0; q < 4; q++) { gA[q] = fng[cb + q * 16 + lr]; bB4[q] = fnb[cb + q * 16 + lr]; }
#pragma unroll
  for (int q = 0; q < 4; q++) {
    const int col = cb + q * 16 + lr;
#pragma unroll
    for (int rh = 0; rh < 2; rh++)
#pragma unroll
      for (int i = 0; i < 4; i++) {
        float v = (acc[q][rh][i] + b4[q] - mu[rh][i]) * rs[rh][i] * gA[q] + bB4[q];
        out[(size_t)(r0 + rh * 16 + lh * 4 + i) * 256 + col] = fmaxf(v, 0.f);
      }
  }
}

// ================= kernel 1: params (unchanged) =================
#define FPITCH 516

__device__ __forceinline__ void red8(float& s, float& q) {
#pragma unroll
  for (int m = 1; m < 8; m <<= 1) { s += __shfl_xor(s, m); q += __shfl_xor(q, m); }
}

__global__ __launch_bounds__(256) void k_params(
    const float* __restrict__ uf, const unsigned short* __restrict__ dynWf,
    const float* __restrict__ dynb, const float* __restrict__ nog,
    const float* __restrict__ nob, float* __restrict__ param_in,
    float* __restrict__ param_out_ln) {
  __shared__ short aT[32 * APITCH];
  __shared__ float fBuf[32 * FPITCH];
  const int t = threadIdx.x;
  const int wv = t >> 6, lane = t & 63, lr = lane & 15, lh = lane >> 4;
  const int r0 = blockIdx.x * 32;
#pragma unroll
  for (int j = 0; j < 8; j++) {
    const int idx4 = j * 256 + t;
    const int row = idx4 >> 6;
    const int c4 = (idx4 & 63) << 2;
    const float4 v = *(const float4*)&uf[(size_t)(r0 + row) * 256 + c4];
    uint2 pk;
    pk.x = cvt_pk(v.x, v.y);
    pk.y = cvt_pk(v.z, v.w);
    *(uint2*)&aT[row * APITCH + c4] = pk;
  }
  __syncthreads();
  bf16x8 a0[8], a1[8];
#pragma unroll
  for (int kk = 0; kk < 8; kk++) {
    a0[kk] = *(const bf16x8*)&aT[lr * APITCH + kk * 32 + lh * 8];
    a1[kk] = *(const bf16x8*)&aT[(16 + lr) * APITCH + kk * 32 + lh * 8];
  }
#pragma unroll 1
  for (int cp = 0; cp < 8; cp++) {
    const int ct = wv * 8 + cp;
    bf16x8 b[8];
#pragma unroll
    for (int kk = 0; kk < 8; kk++)
      b[kk] = *(const bf16x8*)&dynWf[((ct * 8 + kk) * 64 + lane) * 8];
    const float bi = dynb[ct * 16 + lr];
    f32x4 c0 = {0.f, 0.f, 0.f, 0.f}, c1 = c0;
#pragma unroll
    for (int kk = 0; kk < 8; kk++) {
      c0 = __builtin_amdgcn_mfma_f32_16x16x32_bf16(a0[kk], b[kk], c0, 0, 0, 0);
      c1 = __builtin_amdgcn_mfma_f32_16x16x32_bf16(a1[kk], b[kk], c1, 0, 0, 0);
    }
#pragma unroll
    for (int i = 0; i < 4; i++) {
      fBuf[(lh * 4 + i) * FPITCH + ct * 16 + lr] = c0[i] + bi;
      fBuf[(16 + lh * 4 + i) * FPITCH + ct * 16 + lr] = c1[i] + bi;
    }
  }
  __syncthreads();
  const int row = t >> 3, j = t & 7;
  float s = 0.f, q = 0.f;
#pragma unroll
  for (int i = 0; i < 32; i++) {
    float x = fBuf[row * FPITCH + 256 + j + 8 * i];
    s += x; q += x * x;
  }
  red8(s, q);
  const float mu = s * (1.f / 256.f);
  const float rsv = rsqrtf(q * (1.f / 256.f) - mu * mu + EPS);
#pragma unroll 1
  for (int i = 0; i < 32; i++) {
    const int c = j + 8 * i;
    float x = fBuf[row * FPITCH + 256 + c];
    param_out_ln[(size_t)(r0 + row) * 256 + c] = (x - mu) * rsv * nog[c] + nob[c];
  }
#pragma unroll
  for (int jj = 0; jj < 8; jj++) {
    const int idx4 = jj * 256 + t;
    const int rwq = idx4 >> 6;
    const int c4 = (idx4 & 63) << 2;
    float4 v;
    v.x = fBuf[rwq * FPITCH + c4 + 0];
    v.y = fBuf[rwq * FPITCH + c4 + 1];
    v.z = fBuf[rwq * FPITCH + c4 + 2];
    v.w = fBuf[rwq * FPITCH + c4 + 3];
    *(float4*)&param_in[(size_t)(r0 + rwq) * 256 + c4] = v;
  }
}

extern "C" void kernel_launch(void* const* d_in, const int* in_sizes, int n_in,
                              void* d_out, int out_size, void* d_ws, size_t ws_size,
                              hipStream_t stream) {
  const float* uf   = (const float*)d_in[0];
  const float* inf  = (const float*)d_in[1];
  const float* dynW = (const float*)d_in[2];
  const float* dynb = (const float*)d_in[3];
  const float* inpW = (const float*)d_in[4];
  const float* inpb = (const float*)d_in[5];
  const float* igW  = (const float*)d_in[6];
  const float* igb  = (const float*)d_in[7];
  const float* ugW  = (const float*)d_in[8];
  const float* ugb  = (const float*)d_in[9];
  const float* fcW  = (const float*)d_in[10];
  const float* fcb  = (const float*)d_in[11];
  const float* nig  = (const float*)d_in[12];
  const float* nib  = (const float*)d_in[13];
  const float* nog  = (const float*)d_in[14];
  const float* nob  = (const float*)d_in[15];
  const float* iig  = (const float*)d_in[16];
  const float* iib  = (const float*)d_in[17];
  const float* iog  = (const float*)d_in[18];
  const float* iob  = (const float*)d_in[19];
  const float* fng  = (const float*)d_in[20];
  const float* fnb  = (const float*)d_in[21];
  float* out = (float*)d_out;

  char* ws = (char*)d_ws;
  unsigned short* Wf = (unsigned short*)ws;
  unsigned short* dynWf = Wf;
  unsigned short* inpWf = Wf + 131072;
  unsigned short* igWf  = Wf + 262144;
  unsigned short* ugWf  = Wf + 327680;
  unsigned short* fcWf  = Wf + 393216;
  float* param_in     = (float*)(ws + (1 << 20));
  float* param_out_ln = (float*)(ws + (1 << 20) + (16 << 20));

  k_cvt_all<<<dim3(1792), dim3(256), 0, stream>>>(dynW, inpW, igW, ugW, fcW, Wf);

  k_params<<<dim3(512), dim3(256), 0, stream>>>(uf, dynWf, dynb, nog, nob,
                                                param_in, param_out_ln);

  k_main<<<dim3(4608), dim3(256), 0, stream>>>(
      inf, inpWf, inpb, igWf, igb, ugWf, ugb, fcWf, fcb,
      nig, nib, iig, iib, iog, iob, fng, fnb,
      param_in, param_out_ln, out);
}